// Round 16
// baseline (8619.395 us; speedup 1.0000x reference)
//
#include <hip/hip_runtime.h>
#include <hip/hip_bf16.h>
#include <math.h>

#define KW 24
#define BSZn 64
#define PLY 32
#define BROWS 1536            // BSZ*KW rows per task
#define RTOT 4608             // 3*BROWS

typedef __attribute__((ext_vector_type(8))) short short8v;  // 8 bf16 (4 VGPRs)
typedef __attribute__((ext_vector_type(4))) float f32x4;

__device__ __forceinline__ float sigmoidf_(float x) { return 1.0f / (1.0f + expf(-x)); }

// async global->LDS, 16B/lane; LDS dest = wave-uniform base + lane*16 (HW scatter)
__device__ __forceinline__ void gload16(const void* g, void* l)
{
    __builtin_amdgcn_global_load_lds(
        (__attribute__((address_space(1))) void*)g,
        (__attribute__((address_space(3))) void*)l, 16, 0, 0);
}

// exact 3-way bf16 split: v = s0 + s1 + s2 + O(2^-26 v)
__device__ __forceinline__ void split3(float v, ushort* a, ushort* b, ushort* c)
{
    __hip_bfloat16 h1 = __float2bfloat16(v);  float f1 = __bfloat162float(h1);
    float r1 = v - f1;
    __hip_bfloat16 h2 = __float2bfloat16(r1); float f2 = __bfloat162float(h2);
    float r2 = r1 - f2;
    __hip_bfloat16 h3 = __float2bfloat16(r2);
    *a = *(ushort*)&h1; *b = *(ushort*)&h2; *c = *(ushort*)&h3;
}

// ---- weights prep (R9-proven, verbatim) ----
__global__ void prep_split(const float* __restrict__ W_ih, const float* __restrict__ W_hh,
                           const float* __restrict__ Wq,
                           const float* __restrict__ b_ih, const float* __restrict__ b_hh,
                           ushort* __restrict__ Wg0, ushort* __restrict__ Wg1, ushort* __restrict__ Wg2,
                           ushort* __restrict__ Wq0, ushort* __restrict__ Wq1, ushort* __restrict__ Wq2,
                           float* __restrict__ biasG)
{
    int n = blockIdx.x, tid = threadIdx.x;     // 0..2559
    if (n < 2048) {
        int ublk = n >> 6, gate = (n >> 4) & 3, ui = n & 15;
        int src = gate * 512 + ublk * 16 + ui;
        for (int k = tid; k < 1024; k += 256) {
            float v = (k < 512) ? W_ih[(size_t)src * 512 + k]
                                : W_hh[(size_t)src * 512 + (k - 512)];
            ushort s0, s1, s2; split3(v, &s0, &s1, &s2);
            Wg0[(size_t)n * 1024 + k] = s0;
            Wg1[(size_t)n * 1024 + k] = s1;
            Wg2[(size_t)n * 1024 + k] = s2;
        }
        if (tid == 0) biasG[src] = b_ih[src] + b_hh[src];
    } else {
        int n2 = n - 2048;
        for (int k = tid; k < 512; k += 256) {
            ushort s0, s1, s2; split3(Wq[(size_t)n2 * 512 + k], &s0, &s1, &s2);
            Wq0[(size_t)n2 * 512 + k] = s0;
            Wq1[(size_t)n2 * 512 + k] = s1;
            Wq2[(size_t)n2 * 512 + k] = s2;
        }
    }
}

// ---- init (R9-proven, verbatim) ----
__global__ void initsplit(const float* __restrict__ home, const float* __restrict__ vis,
                          const float* __restrict__ team, const float* __restrict__ init_embed,
                          float* __restrict__ cst,
                          ushort* __restrict__ h0_, ushort* __restrict__ h1_, ushort* __restrict__ h2_,
                          ushort* __restrict__ x0_, ushort* __restrict__ x1_, ushort* __restrict__ x2_)
{
    int row = blockIdx.x, tid = threadIdx.x;
    int tau = row / BROWS, r = row % BROWS;
    const float* enc = (tau == 0) ? home : (tau == 1) ? vis : team;
    const float* base = enc + ((size_t)((r % KW) * BSZn + r / KW) * PLY) * 512;
    for (int e = tid; e < 512; e += 256) {
        float s = 0.0f;
        for (int p = 0; p < PLY; ++p) s += base[(size_t)p * 512 + e];
        size_t o = (size_t)row * 512 + e;
        cst[o] = s;
        ushort a, b, c;
        split3(s, &a, &b, &c);
        h0_[o] = a; h1_[o] = b; h2_[o] = c;
        split3(init_embed[e], &a, &b, &c);
        x0_[o] = a; x1_[o] = b; x2_[o] = c;
    }
}

// ---- gather x_{t+1} and split (R9-proven, verbatim) ----
__global__ void xprep(const float* __restrict__ home, const float* __restrict__ vis,
                      const float* __restrict__ team,
                      const int* __restrict__ hidx, const int* __restrict__ vidx,
                      const int* __restrict__ tidx,
                      ushort* __restrict__ x0_, ushort* __restrict__ x1_, ushort* __restrict__ x2_,
                      int t)
{
    int row = blockIdx.x, tid = threadIdx.x;
    int tau = row / BROWS, r = row % BROWS;
    const float* enc = (tau == 0) ? home : (tau == 1) ? vis : team;
    const int* idx = (tau == 0) ? hidx : (tau == 1) ? vidx : tidx;
    int j = idx[r * PLY + t];
    const float* src = enc + ((size_t)((r % KW) * BSZn + r / KW) * PLY + j) * 512;
    for (int e = tid; e < 512; e += 256) {
        size_t o = (size_t)row * 512 + e;
        ushort a, b, c; split3(src[e], &a, &b, &c);
        x0_[o] = a; x1_[o] = b; x2_[o] = c;
    }
}

// ---- gates+q MFMA (R15-proven, verbatim) ----
// bn < 16: gates (K=1024, x|h, LSTM epilogue). bn 16..19: q_{t-1} -> Q[qslot].
__global__ __launch_bounds__(256) void gates_mfma(
    const ushort* __restrict__ x0_, const ushort* __restrict__ x1_, const ushort* __restrict__ x2_,
    const ushort* __restrict__ hi0, const ushort* __restrict__ hi1, const ushort* __restrict__ hi2,
    const ushort* __restrict__ Wg0, const ushort* __restrict__ Wg1, const ushort* __restrict__ Wg2,
    const ushort* __restrict__ Wq0, const ushort* __restrict__ Wq1, const ushort* __restrict__ Wq2,
    const float* __restrict__ biasG, const float* __restrict__ bq,
    float* __restrict__ cst,
    ushort* __restrict__ ho0, ushort* __restrict__ ho1, ushort* __restrict__ ho2,
    float* __restrict__ Q2, int bn_off, int qslot)
{
    __shared__ char Lds[32768];               // A | B0 | B1 | B2
    int tid = threadIdx.x;
    int bm = blockIdx.x, bn = blockIdx.y + bn_off;
    bool isq = bn >= 16;
    int w = tid >> 6, lane = tid & 63;
    int wr = w >> 1, wc = w & 1;
    int r0 = bm * 128;
    int nbase = isq ? (bn - 16) * 128 : bn * 128;
    int ldb = isq ? 512 : 1024;
    int kb0 = isq ? 16 : 0;
    int l4 = lane >> 2, lc = lane & 3;        // loader row-sub / col16

    const ushort* Ax[3] = {x0_, x1_, x2_};
    const ushort* Ah[3] = {hi0, hi1, hi2};
    const ushort* Bp[3];
    if (isq) { Bp[0] = Wq0; Bp[1] = Wq1; Bp[2] = Wq2; }
    else     { Bp[0] = Wg0; Bp[1] = Wg1; Bp[2] = Wg2; }

    f32x4 acc[4][4];
    #pragma unroll
    for (int i = 0; i < 4; ++i)
        #pragma unroll
        for (int j = 0; j < 4; ++j) acc[i][j] = (f32x4){0.f, 0.f, 0.f, 0.f};

    char* ldsW = Lds + w * 2048;              // wave-uniform region base (A region)

    for (int kb = kb0; kb < 32; ++kb) {
        int kloc = (kb & 15) * 32;            // element offset within x- or h-row
        bool usex = (!isq) && (kb < 16);
        int bofe = isq ? kloc : kb * 32;      // element offset within B row
        __syncthreads();                      // prev kb's region reads done
        {
            const ushort* Ap = (usex ? Ax[0] : Ah[0]);
            gload16(Ap + (size_t)(r0 + w * 32 + l4) * 512 + kloc + lc * 8,      ldsW);
            gload16(Ap + (size_t)(r0 + w * 32 + 16 + l4) * 512 + kloc + lc * 8, ldsW + 1024);
            #pragma unroll
            for (int p = 0; p < 3; ++p) {
                gload16(Bp[p] + (size_t)(nbase + w * 32 + l4) * ldb + bofe + lc * 8,
                        ldsW + (1 + p) * 8192);
                gload16(Bp[p] + (size_t)(nbase + w * 32 + 16 + l4) * ldb + bofe + lc * 8,
                        ldsW + (1 + p) * 8192 + 1024);
            }
        }
        __syncthreads();                      // vmcnt(0) drained by compiler

        #pragma unroll
        for (int a = 0; a < 3; ++a) {
            if (a > 0) {
                const ushort* Ap = (usex ? Ax[a] : Ah[a]);
                __syncthreads();              // prev A-plane frag reads done
                gload16(Ap + (size_t)(r0 + w * 32 + l4) * 512 + kloc + lc * 8,      ldsW);
                gload16(Ap + (size_t)(r0 + w * 32 + 16 + l4) * 512 + kloc + lc * 8, ldsW + 1024);
                __syncthreads();
            }
            short8v af[4];
            #pragma unroll
            for (int fm = 0; fm < 4; ++fm)
                af[fm] = *(const short8v*)(Lds + (wr * 64 + fm * 16 + (lane & 15)) * 64 + (lane >> 4) * 16);
            #pragma unroll
            for (int b = 2; b >= 0; --b) {    // smallest products first within group
                if (a + b > 2) continue;
                const char* LdsB = Lds + 8192 + b * 8192;
                short8v bf[4];
                #pragma unroll
                for (int fn = 0; fn < 4; ++fn)
                    bf[fn] = *(const short8v*)(LdsB + (wc * 64 + fn * 16 + (lane & 15)) * 64 + (lane >> 4) * 16);
                #pragma unroll
                for (int fm = 0; fm < 4; ++fm)
                    #pragma unroll
                    for (int fn = 0; fn < 4; ++fn)
                        acc[fm][fn] = __builtin_amdgcn_mfma_f32_16x16x32_bf16(
                            af[fm], bf[fn], acc[fm][fn], 0, 0, 0);
            }
        }
    }

    if (!isq) {
        // LSTM epilogue (R9-proven): frag fn == gate; unit u fixed per lane.
        int u = (bn * 2 + wc) * 16 + (lane & 15);
        float bI = biasG[u], bF = biasG[512 + u], bG = biasG[1024 + u], bO = biasG[1536 + u];
        #pragma unroll
        for (int fm = 0; fm < 4; ++fm) {
            #pragma unroll
            for (int reg = 0; reg < 4; ++reg) {
                int row = r0 + wr * 64 + fm * 16 + (lane >> 4) * 4 + reg;
                float gi = acc[fm][0][reg] + bI;
                float gf = acc[fm][1][reg] + bF;
                float gg = acc[fm][2][reg] + bG;
                float go = acc[fm][3][reg] + bO;
                size_t ci = (size_t)row * 512 + u;
                float c = cst[ci];
                c = sigmoidf_(gf) * c + sigmoidf_(gi) * tanhf(gg);
                float h = sigmoidf_(go) * tanhf(c);
                cst[ci] = c;
                ushort s0, s1, s2; split3(h, &s0, &s1, &s2);
                ho0[ci] = s0; ho1[ci] = s1; ho2[ci] = s2;
            }
        }
    } else {
        float* Qout = Q2 + (size_t)qslot * RTOT * 512;
        #pragma unroll
        for (int fn = 0; fn < 4; ++fn) {
            int col = nbase + wc * 64 + fn * 16 + (lane & 15);
            float bqv = bq[col];
            #pragma unroll
            for (int fm = 0; fm < 4; ++fm)
                #pragma unroll
                for (int reg = 0; reg < 4; ++reg) {
                    int row = r0 + wr * 64 + fm * 16 + (lane >> 4) * 4 + reg;
                    Qout[(size_t)row * 512 + col] = acc[fm][fn][reg] + bqv;
                }
        }
    }
}

// ---- ctx = enc @ Wc^T, f32 (R1-proven kernel, verbatim) ----
#define BM 128
#define BN 128
#define BKK 16
__global__ __launch_bounds__(256) void gemm_ctx(
    const float* __restrict__ A0, const float* __restrict__ A1, const float* __restrict__ A2,
    const float* __restrict__ B, float* __restrict__ C)
{
    __shared__ float As[BKK][BM + 4];
    __shared__ float Bs[BKK][BN + 4];
    int bm = blockIdx.x, bn = blockIdx.y;
    int tid = threadIdx.x;
    int tm = tid >> 4, tn = tid & 15;
    int lrow = tid >> 2, lc4 = tid & 3;

    int R0 = bm * BM;
    int tau = R0 / (BROWS * PLY);
    const float* enc = (tau == 0) ? A0 : (tau == 1) ? A1 : A2;
    int R = R0 + lrow;
    int rr = R % (BROWS * PLY); int r = rr >> 5; int p = rr & 31;
    const float* a_src0 = enc + (((size_t)((r % KW) * BSZn + r / KW)) * PLY + p) * 512;
    R = R0 + lrow + 64;
    rr = R % (BROWS * PLY); r = rr >> 5; p = rr & 31;
    const float* a_src1 = enc + (((size_t)((r % KW) * BSZn + r / KW)) * PLY + p) * 512;
    const float* b_src0 = B + (size_t)(bn * BN + lrow) * 512;
    const float* b_src1 = b_src0 + (size_t)64 * 512;

    float acc[8][8];
    #pragma unroll
    for (int i = 0; i < 8; ++i)
        #pragma unroll
        for (int j = 0; j < 8; ++j) acc[i][j] = 0.0f;

    float4 a0 = *(const float4*)(a_src0 + lc4 * 4);
    float4 a1 = *(const float4*)(a_src1 + lc4 * 4);
    float4 b0 = *(const float4*)(b_src0 + lc4 * 4);
    float4 b1 = *(const float4*)(b_src1 + lc4 * 4);

    for (int t = 0; t < 512 / BKK; ++t) {
        __syncthreads();
        As[lc4 * 4 + 0][lrow] = a0.x; As[lc4 * 4 + 1][lrow] = a0.y;
        As[lc4 * 4 + 2][lrow] = a0.z; As[lc4 * 4 + 3][lrow] = a0.w;
        As[lc4 * 4 + 0][lrow + 64] = a1.x; As[lc4 * 4 + 1][lrow + 64] = a1.y;
        As[lc4 * 4 + 2][lrow + 64] = a1.z; As[lc4 * 4 + 3][lrow + 64] = a1.w;
        Bs[lc4 * 4 + 0][lrow] = b0.x; Bs[lc4 * 4 + 1][lrow] = b0.y;
        Bs[lc4 * 4 + 2][lrow] = b0.z; Bs[lc4 * 4 + 3][lrow] = b0.w;
        Bs[lc4 * 4 + 0][lrow + 64] = b1.x; Bs[lc4 * 4 + 1][lrow + 64] = b1.y;
        Bs[lc4 * 4 + 2][lrow + 64] = b1.z; Bs[lc4 * 4 + 3][lrow + 64] = b1.w;
        __syncthreads();
        if (t + 1 < 512 / BKK) {
            int k0 = (t + 1) * BKK + lc4 * 4;
            a0 = *(const float4*)(a_src0 + k0);
            a1 = *(const float4*)(a_src1 + k0);
            b0 = *(const float4*)(b_src0 + k0);
            b1 = *(const float4*)(b_src1 + k0);
        }
        #pragma unroll
        for (int k = 0; k < BKK; ++k) {
            float af[8], bf[8];
            *(float4*)&af[0] = *(const float4*)&As[k][tm * 8];
            *(float4*)&af[4] = *(const float4*)&As[k][tm * 8 + 4];
            *(float4*)&bf[0] = *(const float4*)&Bs[k][tn * 8];
            *(float4*)&bf[4] = *(const float4*)&Bs[k][tn * 8 + 4];
            #pragma unroll
            for (int i = 0; i < 8; ++i)
                #pragma unroll
                for (int j = 0; j < 8; ++j)
                    acc[i][j] = fmaf(af[i], bf[j], acc[i][j]);
        }
    }
    int row0 = bm * BM + tm * 8;
    int col0 = bn * BN + tn * 8;
    #pragma unroll
    for (int i = 0; i < 8; ++i) {
        float* cr = C + (size_t)(row0 + i) * 512 + col0;
        float4 o0, o1;
        o0.x = acc[i][0]; o0.y = acc[i][1]; o0.z = acc[i][2]; o0.w = acc[i][3];
        o1.x = acc[i][4]; o1.y = acc[i][5]; o1.z = acc[i][6]; o1.w = acc[i][7];
        *(float4*)cr = o0;
        *(float4*)(cr + 4) = o1;
    }
}

// ---- attention, 2 steps per ctx load (R10/R12-proven, verbatim — fallback) ----
__global__ __launch_bounds__(256) void attn2r(
    const float* __restrict__ Q2, const float* __restrict__ ctx,
    const float* __restrict__ vvec, float* __restrict__ out, int tbase)
{
    int row = blockIdx.x, tid = threadIdx.x;
    int w = tid >> 6, lane = tid & 63;
    __shared__ float scs[2][PLY];

    const float* q0 = Q2 + (size_t)row * 512 + lane * 8;                 // slot 0 (even step)
    const float* q1 = Q2 + ((size_t)RTOT + row) * 512 + lane * 8;        // slot 1
    const float* ctxr = ctx + (size_t)row * PLY * 512 + lane * 8;
    float qa[8], qb[8], vv[8];
    *(float4*)&qa[0] = *(const float4*)(q0);
    *(float4*)&qa[4] = *(const float4*)(q0 + 4);
    *(float4*)&qb[0] = *(const float4*)(q1);
    *(float4*)&qb[4] = *(const float4*)(q1 + 4);
    *(float4*)&vv[0] = *(const float4*)(vvec + lane * 8);
    *(float4*)&vv[4] = *(const float4*)(vvec + lane * 8 + 4);

    for (int pp = 0; pp < 8; ++pp) {
        int p = w * 8 + pp;
        const float* cp = ctxr + (size_t)p * 512;
        float cv[8];
        *(float4*)&cv[0] = *(const float4*)(cp);
        *(float4*)&cv[4] = *(const float4*)(cp + 4);
        float a0 = 0.0f, a1 = 0.0f;
        #pragma unroll
        for (int j = 0; j < 8; ++j) {
            a0 += tanhf(qa[j] + cv[j]) * vv[j];
            a1 += tanhf(qb[j] + cv[j]) * vv[j];
        }
        #pragma unroll
        for (int off = 1; off < 64; off <<= 1) {
            a0 += __shfl_xor(a0, off);
            a1 += __shfl_xor(a1, off);
        }
        if (lane == 0) { scs[0][p] = a0; scs[1][p] = a1; }
    }
    __syncthreads();

    if (tid < 64) {
        int w2 = tid >> 5, l = tid & 31;
        float x = scs[w2][l];
        float bvv = x; int bi = l;
        #pragma unroll
        for (int off = 1; off < 32; off <<= 1) {
            float ov = __shfl_xor(bvv, off, 32);
            int oi = __shfl_xor(bi, off, 32);
            if (ov > bvv || (ov == bvv && oi < bi)) { bvv = ov; bi = oi; }
        }
        float s = expf(x - bvv);
        #pragma unroll
        for (int off = 1; off < 32; off <<= 1) s += __shfl_xor(s, off, 32);
        float lse = logf(s);
        int t = tbase + w2;
        int tau = row / BROWS, r = row % BROWS;
        out[(size_t)tau * (BROWS * 1024) + (size_t)r * 1024 + t * 32 + l] = x - bvv - lse;
        if (l == 0)
            out[(size_t)3 * (BROWS * 1024) + (size_t)tau * (BROWS * 32) + r * 32 + t] = (float)bi;
    }
}

// ---- attention, 4 steps per ctx load (tbase%4==0; q_s at slot s%4 = slot i) ----
__global__ __launch_bounds__(256) void attn4r(
    const float* __restrict__ Q4, const float* __restrict__ ctx,
    const float* __restrict__ vvec, float* __restrict__ out, int tbase)
{
    int row = blockIdx.x, tid = threadIdx.x;
    int w = tid >> 6, lane = tid & 63;
    __shared__ float scs[4][PLY];

    float qv[4][8], vv[8];
    #pragma unroll
    for (int s = 0; s < 4; ++s) {
        const float* q = Q4 + ((size_t)s * RTOT + row) * 512 + lane * 8;
        *(float4*)&qv[s][0] = *(const float4*)(q);
        *(float4*)&qv[s][4] = *(const float4*)(q + 4);
    }
    *(float4*)&vv[0] = *(const float4*)(vvec + lane * 8);
    *(float4*)&vv[4] = *(const float4*)(vvec + lane * 8 + 4);
    const float* ctxr = ctx + (size_t)row * PLY * 512 + lane * 8;

    for (int pp = 0; pp < 8; ++pp) {
        int p = w * 8 + pp;
        const float* cp = ctxr + (size_t)p * 512;
        float cv[8];
        *(float4*)&cv[0] = *(const float4*)(cp);
        *(float4*)&cv[4] = *(const float4*)(cp + 4);
        float a[4] = {0.f, 0.f, 0.f, 0.f};
        #pragma unroll
        for (int j = 0; j < 8; ++j) {
            float c = cv[j], ve = vv[j];
            #pragma unroll
            for (int s = 0; s < 4; ++s)
                a[s] += tanhf(qv[s][j] + c) * ve;
        }
        #pragma unroll
        for (int off = 1; off < 64; off <<= 1) {
            #pragma unroll
            for (int s = 0; s < 4; ++s) a[s] += __shfl_xor(a[s], off);
        }
        if (lane == 0) {
            #pragma unroll
            for (int s = 0; s < 4; ++s) scs[s][p] = a[s];
        }
    }
    __syncthreads();

    if (tid < 128) {
        int w2 = tid >> 5, l = tid & 31;
        float x = scs[w2][l];
        float bvv = x; int bi = l;
        #pragma unroll
        for (int off = 1; off < 32; off <<= 1) {
            float ov = __shfl_xor(bvv, off, 32);
            int oi = __shfl_xor(bi, off, 32);
            if (ov > bvv || (ov == bvv && oi < bi)) { bvv = ov; bi = oi; }
        }
        float s = expf(x - bvv);
        #pragma unroll
        for (int off = 1; off < 32; off <<= 1) s += __shfl_xor(s, off, 32);
        float lse = logf(s);
        int t = tbase + w2;
        int tau = row / BROWS, r = row % BROWS;
        out[(size_t)tau * (BROWS * 1024) + (size_t)r * 1024 + t * 32 + l] = x - bvv - lse;
        if (l == 0)
            out[(size_t)3 * (BROWS * 1024) + (size_t)tau * (BROWS * 32) + r * 32 + t] = (float)bi;
    }
}

extern "C" void kernel_launch(void* const* d_in, const int* in_sizes, int n_in,
                              void* d_out, int out_size, void* d_ws, size_t ws_size,
                              hipStream_t stream)
{
    const float* home = (const float*)d_in[0];
    const int*   hidx = (const int*)d_in[1];
    const float* vis  = (const float*)d_in[2];
    const int*   vidx = (const int*)d_in[3];
    const float* team = (const float*)d_in[4];
    const int*   tidx = (const int*)d_in[5];
    const float* init_embed = (const float*)d_in[6];
    const float* W_ih = (const float*)d_in[7];
    const float* W_hh = (const float*)d_in[8];
    const float* b_ih = (const float*)d_in[9];
    const float* b_hh = (const float*)d_in[10];
    const float* Wq   = (const float*)d_in[11];
    const float* bq   = (const float*)d_in[12];
    const float* Wc   = (const float*)d_in[13];
    const float* vvec = (const float*)d_in[14];
    float* out = (float*)d_out;
    (void)in_sizes; (void)n_in; (void)out_size;

    // Q4 layout needs 405,807,104 B; Q2 layout (R15-proven) needs 386,932,736 B.
    const size_t NEED_Q4 = 405807104ULL;
    bool use4 = (ws_size >= NEED_Q4);
    int QS = use4 ? 4 : 2;

    char* wsb = (char*)d_ws;
    float* ctx   = (float*)wsb; wsb += (size_t)RTOT * PLY * 512 * 4;   // 302.0 MB
    float* cst   = (float*)wsb; wsb += (size_t)RTOT * 512 * 4;         // 9.4 MB
    float* Q     = (float*)wsb; wsb += (size_t)QS * RTOT * 512 * 4;    // 18.9 / 37.7 MB
    float* biasG = (float*)wsb; wsb += 2048 * 4;
    ushort* Wg[3], *Wq3[3], *xs[3], *hs[2][3];
    for (int i = 0; i < 3; ++i) { Wg[i]  = (ushort*)wsb; wsb += (size_t)2048 * 1024 * 2; }
    for (int i = 0; i < 3; ++i) { Wq3[i] = (ushort*)wsb; wsb += (size_t)512 * 512 * 2; }
    for (int i = 0; i < 3; ++i) { xs[i]  = (ushort*)wsb; wsb += (size_t)RTOT * 512 * 2; }
    for (int b = 0; b < 2; ++b)
        for (int i = 0; i < 3; ++i) { hs[b][i] = (ushort*)wsb; wsb += (size_t)RTOT * 512 * 2; }

    prep_split<<<2560, 256, 0, stream>>>(W_ih, W_hh, Wq, b_ih, b_hh,
                                         Wg[0], Wg[1], Wg[2], Wq3[0], Wq3[1], Wq3[2], biasG);
    initsplit<<<RTOT, 256, 0, stream>>>(home, vis, team, init_embed, cst,
                                        hs[1][0], hs[1][1], hs[1][2],
                                        xs[0], xs[1], xs[2]);
    gemm_ctx<<<dim3(RTOT * PLY / BM, 512 / BN), 256, 0, stream>>>(home, vis, team, Wc, ctx);

    for (int t = 0; t < 32; ++t) {
        int hin = (t + 1) & 1, hout = t & 1;
        int gy = 16 + ((t >= 1) ? 4 : 0);      // t>=1: fuse q_{t-1} (A == hin)
        gates_mfma<<<dim3(36, gy), 256, 0, stream>>>(
            xs[0], xs[1], xs[2],
            hs[hin][0], hs[hin][1], hs[hin][2],
            Wg[0], Wg[1], Wg[2], Wq3[0], Wq3[1], Wq3[2],
            biasG, bq, cst,
            hs[hout][0], hs[hout][1], hs[hout][2],
            Q, 0, (t - 1) & (QS - 1));
        if (t < 31)
            xprep<<<RTOT, 256, 0, stream>>>(home, vis, team, hidx, vidx, tidx,
                                            xs[0], xs[1], xs[2], t);
        if (use4) {
            if (t >= 4 && (t & 3) == 0)       // q(t-4..t-1) in slots 0..3
                attn4r<<<RTOT, 256, 0, stream>>>(Q, ctx, vvec, out, t - 4);
        } else {
            if (t >= 2 && (t & 1) == 0)       // q(t-2),q(t-1) ready
                attn2r<<<RTOT, 256, 0, stream>>>(Q, ctx, vvec, out, t - 2);
        }
    }
    // tail: q_31 from h_31 (hs[1]); q-only launch (bn_off=16)
    gates_mfma<<<dim3(36, 4), 256, 0, stream>>>(
        xs[0], xs[1], xs[2],
        hs[1][0], hs[1][1], hs[1][2],
        Wg[0], Wg[1], Wg[2], Wq3[0], Wq3[1], Wq3[2],
        biasG, bq, cst,
        hs[0][0], hs[0][1], hs[0][2],
        Q, 16, 31 & (QS - 1));
    if (use4)
        attn4r<<<RTOT, 256, 0, stream>>>(Q, ctx, vvec, out, 28);
    else
        attn2r<<<RTOT, 256, 0, stream>>>(Q, ctx, vvec, out, 30);
}

// Round 17
// 7621.292 us; speedup vs baseline: 1.1310x; 1.1310x over previous
//
#include <hip/hip_runtime.h>
#include <hip/hip_bf16.h>
#include <math.h>

#define KW 24
#define BSZn 64
#define PLY 32
#define BROWS 1536            // BSZ*KW rows per task
#define RTOT 4608             // 3*BROWS

typedef __attribute__((ext_vector_type(8))) short short8v;  // 8 bf16 (4 VGPRs)
typedef __attribute__((ext_vector_type(4))) float f32x4;

__device__ __forceinline__ float sigmoidf_(float x) { return 1.0f / (1.0f + expf(-x)); }

// async global->LDS, 16B/lane; LDS dest = wave-uniform base + lane*16 (HW scatter)
__device__ __forceinline__ void gload16(const void* g, void* l)
{
    __builtin_amdgcn_global_load_lds(
        (__attribute__((address_space(1))) void*)g,
        (__attribute__((address_space(3))) void*)l, 16, 0, 0);
}

// exact 3-way bf16 split: v = s0 + s1 + s2 + O(2^-26 v)
__device__ __forceinline__ void split3(float v, ushort* a, ushort* b, ushort* c)
{
    __hip_bfloat16 h1 = __float2bfloat16(v);  float f1 = __bfloat162float(h1);
    float r1 = v - f1;
    __hip_bfloat16 h2 = __float2bfloat16(r1); float f2 = __bfloat162float(h2);
    float r2 = r1 - f2;
    __hip_bfloat16 h3 = __float2bfloat16(r2);
    *a = *(ushort*)&h1; *b = *(ushort*)&h2; *c = *(ushort*)&h3;
}

// ---- weights prep (R9-proven; weights-only) ----
__global__ void prep_split(const float* __restrict__ W_ih, const float* __restrict__ W_hh,
                           const float* __restrict__ Wq,
                           const float* __restrict__ b_ih, const float* __restrict__ b_hh,
                           ushort* __restrict__ Wg0, ushort* __restrict__ Wg1, ushort* __restrict__ Wg2,
                           ushort* __restrict__ Wq0, ushort* __restrict__ Wq1, ushort* __restrict__ Wq2,
                           float* __restrict__ biasG)
{
    int n = blockIdx.x, tid = threadIdx.x;     // 0..2559
    if (n < 2048) {
        int ublk = n >> 6, gate = (n >> 4) & 3, ui = n & 15;
        int src = gate * 512 + ublk * 16 + ui;
        for (int k = tid; k < 1024; k += 256) {
            float v = (k < 512) ? W_ih[(size_t)src * 512 + k]
                                : W_hh[(size_t)src * 512 + (k - 512)];
            ushort s0, s1, s2; split3(v, &s0, &s1, &s2);
            Wg0[(size_t)n * 1024 + k] = s0;
            Wg1[(size_t)n * 1024 + k] = s1;
            Wg2[(size_t)n * 1024 + k] = s2;
        }
        if (tid == 0) biasG[src] = b_ih[src] + b_hh[src];
    } else {
        int n2 = n - 2048;
        for (int k = tid; k < 512; k += 256) {
            ushort s0, s1, s2; split3(Wq[(size_t)n2 * 512 + k], &s0, &s1, &s2);
            Wq0[(size_t)n2 * 512 + k] = s0;
            Wq1[(size_t)n2 * 512 + k] = s1;
            Wq2[(size_t)n2 * 512 + k] = s2;
        }
    }
}

// ---- init: cst = hf0 = h0 = enc.sum(axis=1), all f32 ----
__global__ void init0(const float* __restrict__ home, const float* __restrict__ vis,
                      const float* __restrict__ team,
                      float* __restrict__ cst, float* __restrict__ hf0)
{
    int row = blockIdx.x, tid = threadIdx.x;
    int tau = row / BROWS, r = row % BROWS;
    const float* enc = (tau == 0) ? home : (tau == 1) ? vis : team;
    const float* base = enc + ((size_t)((r % KW) * BSZn + r / KW) * PLY) * 512;
    for (int e = tid; e < 512; e += 256) {
        float s = 0.0f;
        for (int p = 0; p < PLY; ++p) s += base[(size_t)p * 512 + e];
        size_t o = (size_t)row * 512 + e;
        cst[o] = s;
        hf0[o] = s;
    }
}

// ---- gates+q MFMA v17: A staged f32 + split3 in-kernel (all 3 planes at once) ----
// bn < 16: gates (K=1024, x|h, LSTM epilogue -> cst, hf_out f32).
// bn 16..19: q_{t-1} = h @ Wq^T + bq -> Q4 slot qslot (K = h half, kb 16..31).
// x gathered directly from enc[idx[r][t-1]] (t==0: init_embed). 2 barriers/kb.
// LDS 48KB: A0|A1|A2 at p*8192, B0|B1|B2 at 24576+p*8192 (B via gload16, proven).
// Split values/product order identical to R15 -> bitwise-same accumulators.
__global__ __launch_bounds__(256) void gates_mfma(
    const float* __restrict__ home, const float* __restrict__ vis, const float* __restrict__ team,
    const int* __restrict__ hidx, const int* __restrict__ vidx, const int* __restrict__ tidx,
    const float* __restrict__ init_embed,
    const float* __restrict__ hf_in,
    const ushort* __restrict__ Wg0, const ushort* __restrict__ Wg1, const ushort* __restrict__ Wg2,
    const ushort* __restrict__ Wq0, const ushort* __restrict__ Wq1, const ushort* __restrict__ Wq2,
    const float* __restrict__ biasG, const float* __restrict__ bq,
    float* __restrict__ cst, float* __restrict__ hf_out,
    float* __restrict__ Q4, int bn_off, int qslot, int t)
{
    __shared__ char Lds[49152];               // A0|A1|A2 | B0|B1|B2 (8KB each)
    int tid = threadIdx.x;
    int bm = blockIdx.x, bn = blockIdx.y + bn_off;
    bool isq = bn >= 16;
    int w = tid >> 6, lane = tid & 63;
    int wr = w >> 1, wc = w & 1;
    int r0 = bm * 128;
    int nbase = isq ? (bn - 16) * 128 : bn * 128;
    int ldb = isq ? 512 : 1024;
    int kb0 = isq ? 16 : 0;
    int l4 = lane >> 2, lc = lane & 3;        // B loader row-sub / col16
    int srow = tid >> 1, sh = tid & 1;        // A stager: row, 16-float half

    // A row pointers (f32)
    const float* hrow = hf_in + (size_t)(r0 + srow) * 512;
    const float* xrow = init_embed;
    if (!isq && t > 0) {
        int tau = (bm * 128) / BROWS;
        const float* enc = (tau == 0) ? home : (tau == 1) ? vis : team;
        const int* idx = (tau == 0) ? hidx : (tau == 1) ? vidx : tidx;
        int r = r0 + srow - tau * BROWS;
        int j = idx[r * PLY + (t - 1)];
        xrow = enc + ((size_t)((r % KW) * BSZn + r / KW) * PLY + j) * 512;
    }
    const ushort* Bp[3];
    if (isq) { Bp[0] = Wq0; Bp[1] = Wq1; Bp[2] = Wq2; }
    else     { Bp[0] = Wg0; Bp[1] = Wg1; Bp[2] = Wg2; }

    f32x4 acc[4][4];
    #pragma unroll
    for (int i = 0; i < 4; ++i)
        #pragma unroll
        for (int j = 0; j < 4; ++j) acc[i][j] = (f32x4){0.f, 0.f, 0.f, 0.f};

    char* ldsBw = Lds + 24576 + w * 2048;     // per-wave B dest base (plane += 8192)
    char* aw = Lds + srow * 64 + sh * 32;     // per-thread A dest (plane += 8192)

    for (int kb = kb0; kb < 32; ++kb) {
        int kloc = (kb & 15) * 32;
        const float* src = (!isq && kb < 16) ? xrow : hrow;
        float fv[16];
        *(float4*)&fv[0]  = *(const float4*)(src + kloc + sh * 16);
        *(float4*)&fv[4]  = *(const float4*)(src + kloc + sh * 16 + 4);
        *(float4*)&fv[8]  = *(const float4*)(src + kloc + sh * 16 + 8);
        *(float4*)&fv[12] = *(const float4*)(src + kloc + sh * 16 + 12);
        int bofe = isq ? kloc : kb * 32;
        __syncthreads();                      // prev kb's frag reads done
        #pragma unroll
        for (int p = 0; p < 3; ++p) {         // B planes async (proven path)
            gload16(Bp[p] + (size_t)(nbase + w * 32 + l4) * ldb + bofe + lc * 8,
                    ldsBw + p * 8192);
            gload16(Bp[p] + (size_t)(nbase + w * 32 + 16 + l4) * ldb + bofe + lc * 8,
                    ldsBw + p * 8192 + 1024);
        }
        // split A -> 3 planes, one shot
        union { ushort u[16]; uint4 v[2]; } u0, u1, u2;
        #pragma unroll
        for (int j2 = 0; j2 < 16; ++j2) split3(fv[j2], &u0.u[j2], &u1.u[j2], &u2.u[j2]);
        *(uint4*)(aw)              = u0.v[0];
        *(uint4*)(aw + 16)         = u0.v[1];
        *(uint4*)(aw + 8192)       = u1.v[0];
        *(uint4*)(aw + 8192 + 16)  = u1.v[1];
        *(uint4*)(aw + 16384)      = u2.v[0];
        *(uint4*)(aw + 16384 + 16) = u2.v[1];
        __syncthreads();                      // drains lgkm + vmcnt

        #pragma unroll
        for (int a = 0; a < 3; ++a) {
            short8v af[4];
            #pragma unroll
            for (int fm = 0; fm < 4; ++fm)
                af[fm] = *(const short8v*)(Lds + a * 8192 +
                           (wr * 64 + fm * 16 + (lane & 15)) * 64 + (lane >> 4) * 16);
            #pragma unroll
            for (int b = 2; b >= 0; --b) {    // smallest products first within group
                if (a + b > 2) continue;
                const char* LdsB = Lds + 24576 + b * 8192;
                short8v bf[4];
                #pragma unroll
                for (int fn = 0; fn < 4; ++fn)
                    bf[fn] = *(const short8v*)(LdsB +
                               (wc * 64 + fn * 16 + (lane & 15)) * 64 + (lane >> 4) * 16);
                #pragma unroll
                for (int fm = 0; fm < 4; ++fm)
                    #pragma unroll
                    for (int fn = 0; fn < 4; ++fn)
                        acc[fm][fn] = __builtin_amdgcn_mfma_f32_16x16x32_bf16(
                            af[fm], bf[fn], acc[fm][fn], 0, 0, 0);
            }
        }
    }

    if (!isq) {
        // LSTM epilogue (R9-proven math): frag fn == gate; unit u fixed per lane.
        int u = (bn * 2 + wc) * 16 + (lane & 15);
        float bI = biasG[u], bF = biasG[512 + u], bG = biasG[1024 + u], bO = biasG[1536 + u];
        #pragma unroll
        for (int fm = 0; fm < 4; ++fm) {
            #pragma unroll
            for (int reg = 0; reg < 4; ++reg) {
                int row = r0 + wr * 64 + fm * 16 + (lane >> 4) * 4 + reg;
                float gi = acc[fm][0][reg] + bI;
                float gf = acc[fm][1][reg] + bF;
                float gg = acc[fm][2][reg] + bG;
                float go = acc[fm][3][reg] + bO;
                size_t ci = (size_t)row * 512 + u;
                float c = cst[ci];
                c = sigmoidf_(gf) * c + sigmoidf_(gi) * tanhf(gg);
                float h = sigmoidf_(go) * tanhf(c);
                cst[ci] = c;
                hf_out[ci] = h;               // f32, single store (split happens on re-stage)
            }
        }
    } else {
        float* Qout = Q4 + (size_t)qslot * RTOT * 512;
        #pragma unroll
        for (int fn = 0; fn < 4; ++fn) {
            int col = nbase + wc * 64 + fn * 16 + (lane & 15);
            float bqv = bq[col];
            #pragma unroll
            for (int fm = 0; fm < 4; ++fm)
                #pragma unroll
                for (int reg = 0; reg < 4; ++reg) {
                    int row = r0 + wr * 64 + fm * 16 + (lane >> 4) * 4 + reg;
                    Qout[(size_t)row * 512 + col] = acc[fm][fn][reg] + bqv;
                }
        }
    }
}

// ---- ctx = enc @ Wc^T, f32 (R1-proven kernel, verbatim) ----
#define BM 128
#define BN 128
#define BKK 16
__global__ __launch_bounds__(256) void gemm_ctx(
    const float* __restrict__ A0, const float* __restrict__ A1, const float* __restrict__ A2,
    const float* __restrict__ B, float* __restrict__ C)
{
    __shared__ float As[BKK][BM + 4];
    __shared__ float Bs[BKK][BN + 4];
    int bm = blockIdx.x, bn = blockIdx.y;
    int tid = threadIdx.x;
    int tm = tid >> 4, tn = tid & 15;
    int lrow = tid >> 2, lc4 = tid & 3;

    int R0 = bm * BM;
    int tau = R0 / (BROWS * PLY);
    const float* enc = (tau == 0) ? A0 : (tau == 1) ? A1 : A2;
    int R = R0 + lrow;
    int rr = R % (BROWS * PLY); int r = rr >> 5; int p = rr & 31;
    const float* a_src0 = enc + (((size_t)((r % KW) * BSZn + r / KW)) * PLY + p) * 512;
    R = R0 + lrow + 64;
    rr = R % (BROWS * PLY); r = rr >> 5; p = rr & 31;
    const float* a_src1 = enc + (((size_t)((r % KW) * BSZn + r / KW)) * PLY + p) * 512;
    const float* b_src0 = B + (size_t)(bn * BN + lrow) * 512;
    const float* b_src1 = b_src0 + (size_t)64 * 512;

    float acc[8][8];
    #pragma unroll
    for (int i = 0; i < 8; ++i)
        #pragma unroll
        for (int j = 0; j < 8; ++j) acc[i][j] = 0.0f;

    float4 a0 = *(const float4*)(a_src0 + lc4 * 4);
    float4 a1 = *(const float4*)(a_src1 + lc4 * 4);
    float4 b0 = *(const float4*)(b_src0 + lc4 * 4);
    float4 b1 = *(const float4*)(b_src1 + lc4 * 4);

    for (int t = 0; t < 512 / BKK; ++t) {
        __syncthreads();
        As[lc4 * 4 + 0][lrow] = a0.x; As[lc4 * 4 + 1][lrow] = a0.y;
        As[lc4 * 4 + 2][lrow] = a0.z; As[lc4 * 4 + 3][lrow] = a0.w;
        As[lc4 * 4 + 0][lrow + 64] = a1.x; As[lc4 * 4 + 1][lrow + 64] = a1.y;
        As[lc4 * 4 + 2][lrow + 64] = a1.z; As[lc4 * 4 + 3][lrow + 64] = a1.w;
        Bs[lc4 * 4 + 0][lrow] = b0.x; Bs[lc4 * 4 + 1][lrow] = b0.y;
        Bs[lc4 * 4 + 2][lrow] = b0.z; Bs[lc4 * 4 + 3][lrow] = b0.w;
        Bs[lc4 * 4 + 0][lrow + 64] = b1.x; Bs[lc4 * 4 + 1][lrow + 64] = b1.y;
        Bs[lc4 * 4 + 2][lrow + 64] = b1.z; Bs[lc4 * 4 + 3][lrow + 64] = b1.w;
        __syncthreads();
        if (t + 1 < 512 / BKK) {
            int k0 = (t + 1) * BKK + lc4 * 4;
            a0 = *(const float4*)(a_src0 + k0);
            a1 = *(const float4*)(a_src1 + k0);
            b0 = *(const float4*)(b_src0 + k0);
            b1 = *(const float4*)(b_src1 + k0);
        }
        #pragma unroll
        for (int k = 0; k < BKK; ++k) {
            float af[8], bf[8];
            *(float4*)&af[0] = *(const float4*)&As[k][tm * 8];
            *(float4*)&af[4] = *(const float4*)&As[k][tm * 8 + 4];
            *(float4*)&bf[0] = *(const float4*)&Bs[k][tn * 8];
            *(float4*)&bf[4] = *(const float4*)&Bs[k][tn * 8 + 4];
            #pragma unroll
            for (int i = 0; i < 8; ++i)
                #pragma unroll
                for (int j = 0; j < 8; ++j)
                    acc[i][j] = fmaf(af[i], bf[j], acc[i][j]);
        }
    }
    int row0 = bm * BM + tm * 8;
    int col0 = bn * BN + tn * 8;
    #pragma unroll
    for (int i = 0; i < 8; ++i) {
        float* cr = C + (size_t)(row0 + i) * 512 + col0;
        float4 o0, o1;
        o0.x = acc[i][0]; o0.y = acc[i][1]; o0.z = acc[i][2]; o0.w = acc[i][3];
        o1.x = acc[i][4]; o1.y = acc[i][5]; o1.z = acc[i][6]; o1.w = acc[i][7];
        *(float4*)cr = o0;
        *(float4*)(cr + 4) = o1;
    }
}

// ---- attention, 4 steps per ctx load (tbase%4==0; q_s in slot s&3) ----
__global__ __launch_bounds__(256) void attn4r(
    const float* __restrict__ Q4, const float* __restrict__ ctx,
    const float* __restrict__ vvec, float* __restrict__ out, int tbase)
{
    int row = blockIdx.x, tid = threadIdx.x;
    int w = tid >> 6, lane = tid & 63;
    __shared__ float scs[4][PLY];

    float qv[4][8], vv[8];
    #pragma unroll
    for (int s = 0; s < 4; ++s) {
        const float* q = Q4 + ((size_t)s * RTOT + row) * 512 + lane * 8;
        *(float4*)&qv[s][0] = *(const float4*)(q);
        *(float4*)&qv[s][4] = *(const float4*)(q + 4);
    }
    *(float4*)&vv[0] = *(const float4*)(vvec + lane * 8);
    *(float4*)&vv[4] = *(const float4*)(vvec + lane * 8 + 4);
    const float* ctxr = ctx + (size_t)row * PLY * 512 + lane * 8;

    for (int pp = 0; pp < 8; ++pp) {
        int p = w * 8 + pp;
        const float* cp = ctxr + (size_t)p * 512;
        float cv[8];
        *(float4*)&cv[0] = *(const float4*)(cp);
        *(float4*)&cv[4] = *(const float4*)(cp + 4);
        float a[4] = {0.f, 0.f, 0.f, 0.f};
        #pragma unroll
        for (int j = 0; j < 8; ++j) {
            float c = cv[j], ve = vv[j];
            #pragma unroll
            for (int s = 0; s < 4; ++s)
                a[s] += tanhf(qv[s][j] + c) * ve;
        }
        #pragma unroll
        for (int off = 1; off < 64; off <<= 1) {
            #pragma unroll
            for (int s = 0; s < 4; ++s) a[s] += __shfl_xor(a[s], off);
        }
        if (lane == 0) {
            #pragma unroll
            for (int s = 0; s < 4; ++s) scs[s][p] = a[s];
        }
    }
    __syncthreads();

    if (tid < 128) {
        int w2 = tid >> 5, l = tid & 31;
        float x = scs[w2][l];
        float bvv = x; int bi = l;
        #pragma unroll
        for (int off = 1; off < 32; off <<= 1) {
            float ov = __shfl_xor(bvv, off, 32);
            int oi = __shfl_xor(bi, off, 32);
            if (ov > bvv || (ov == bvv && oi < bi)) { bvv = ov; bi = oi; }
        }
        float s = expf(x - bvv);
        #pragma unroll
        for (int off = 1; off < 32; off <<= 1) s += __shfl_xor(s, off, 32);
        float lse = logf(s);
        int t = tbase + w2;
        int tau = row / BROWS, r = row % BROWS;
        out[(size_t)tau * (BROWS * 1024) + (size_t)r * 1024 + t * 32 + l] = x - bvv - lse;
        if (l == 0)
            out[(size_t)3 * (BROWS * 1024) + (size_t)tau * (BROWS * 32) + r * 32 + t] = (float)bi;
    }
}

extern "C" void kernel_launch(void* const* d_in, const int* in_sizes, int n_in,
                              void* d_out, int out_size, void* d_ws, size_t ws_size,
                              hipStream_t stream)
{
    const float* home = (const float*)d_in[0];
    const int*   hidx = (const int*)d_in[1];
    const float* vis  = (const float*)d_in[2];
    const int*   vidx = (const int*)d_in[3];
    const float* team = (const float*)d_in[4];
    const int*   tidx = (const int*)d_in[5];
    const float* init_embed = (const float*)d_in[6];
    const float* W_ih = (const float*)d_in[7];
    const float* W_hh = (const float*)d_in[8];
    const float* b_ih = (const float*)d_in[9];
    const float* b_hh = (const float*)d_in[10];
    const float* Wq   = (const float*)d_in[11];
    const float* bq   = (const float*)d_in[12];
    const float* Wc   = (const float*)d_in[13];
    const float* vvec = (const float*)d_in[14];
    float* out = (float*)d_out;
    (void)in_sizes; (void)n_in; (void)out_size; (void)ws_size;

    char* wsb = (char*)d_ws;
    float* ctx   = (float*)wsb; wsb += (size_t)RTOT * PLY * 512 * 4;   // 302.0 MB
    float* cst   = (float*)wsb; wsb += (size_t)RTOT * 512 * 4;         // 9.4 MB
    float* Q4    = (float*)wsb; wsb += (size_t)4 * RTOT * 512 * 4;     // 37.7 MB
    float* biasG = (float*)wsb; wsb += 2048 * 4;
    ushort* Wg[3], *Wq3[3];
    for (int i = 0; i < 3; ++i) { Wg[i]  = (ushort*)wsb; wsb += (size_t)2048 * 1024 * 2; } // 12.6 MB
    for (int i = 0; i < 3; ++i) { Wq3[i] = (ushort*)wsb; wsb += (size_t)512 * 512 * 2; }   // 1.6 MB
    float* hf[2];
    for (int b = 0; b < 2; ++b) { hf[b] = (float*)wsb; wsb += (size_t)RTOT * 512 * 4; }    // 18.9 MB
    // total 382.2 MB (< 388.0 MB proven in R1)

    prep_split<<<2560, 256, 0, stream>>>(W_ih, W_hh, Wq, b_ih, b_hh,
                                         Wg[0], Wg[1], Wg[2], Wq3[0], Wq3[1], Wq3[2], biasG);
    init0<<<RTOT, 256, 0, stream>>>(home, vis, team, cst, hf[1]);
    gemm_ctx<<<dim3(RTOT * PLY / BM, 512 / BN), 256, 0, stream>>>(home, vis, team, Wc, ctx);

    for (int t = 0; t < 32; ++t) {
        int hin = (t + 1) & 1, hout = t & 1;
        int gy = 16 + ((t >= 1) ? 4 : 0);      // t>=1: fuse q_{t-1} (A == hf[hin])
        gates_mfma<<<dim3(36, gy), 256, 0, stream>>>(
            home, vis, team, hidx, vidx, tidx, init_embed,
            hf[hin],
            Wg[0], Wg[1], Wg[2], Wq3[0], Wq3[1], Wq3[2],
            biasG, bq, cst, hf[hout],
            Q4, 0, (t - 1) & 3, t);
        if (t >= 4 && (t & 3) == 0)           // q(t-4..t-1) in slots 0..3
            attn4r<<<RTOT, 256, 0, stream>>>(Q4, ctx, vvec, out, t - 4);
    }
    // tail: q_31 from h_31 (hf[1], since t=31 wrote hout=hf[1]); q-only (bn_off=16), slot 3
    gates_mfma<<<dim3(36, 4), 256, 0, stream>>>(
        home, vis, team, hidx, vidx, tidx, init_embed,
        hf[1],
        Wg[0], Wg[1], Wg[2], Wq3[0], Wq3[1], Wq3[2],
        biasG, bq, cst, hf[0],
        Q4, 16, 3, 32);
    attn4r<<<RTOT, 256, 0, stream>>>(Q4, ctx, vvec, out, 28);
}

// Round 18
// 7110.537 us; speedup vs baseline: 1.2122x; 1.0718x over previous
//
#include <hip/hip_runtime.h>
#include <hip/hip_bf16.h>
#include <math.h>

#define KW 24
#define BSZn 64
#define PLY 32
#define BROWS 1536            // BSZ*KW rows per task
#define RTOT 4608             // 3*BROWS

typedef __attribute__((ext_vector_type(8))) short short8v;  // 8 bf16 (4 VGPRs)
typedef __attribute__((ext_vector_type(4))) float f32x4;

__device__ __forceinline__ float sigmoidf_(float x) { return 1.0f / (1.0f + expf(-x)); }

// async global->LDS, 16B/lane; LDS dest = wave-uniform base + lane*16 (HW scatter)
__device__ __forceinline__ void gload16(const void* g, void* l)
{
    __builtin_amdgcn_global_load_lds(
        (__attribute__((address_space(1))) void*)g,
        (__attribute__((address_space(3))) void*)l, 16, 0, 0);
}

// exact 3-way bf16 split: v = s0 + s1 + s2 + O(2^-26 v)
__device__ __forceinline__ void split3(float v, ushort* a, ushort* b, ushort* c)
{
    __hip_bfloat16 h1 = __float2bfloat16(v);  float f1 = __bfloat162float(h1);
    float r1 = v - f1;
    __hip_bfloat16 h2 = __float2bfloat16(r1); float f2 = __bfloat162float(h2);
    float r2 = r1 - f2;
    __hip_bfloat16 h3 = __float2bfloat16(r2);
    *a = *(ushort*)&h1; *b = *(ushort*)&h2; *c = *(ushort*)&h3;
}

// ---- weights prep (R9-proven; + Wc planes for ctx-MFMA) ----
__global__ void prep_split(const float* __restrict__ W_ih, const float* __restrict__ W_hh,
                           const float* __restrict__ Wq, const float* __restrict__ Wc,
                           const float* __restrict__ b_ih, const float* __restrict__ b_hh,
                           ushort* __restrict__ Wg0, ushort* __restrict__ Wg1, ushort* __restrict__ Wg2,
                           ushort* __restrict__ Wq0, ushort* __restrict__ Wq1, ushort* __restrict__ Wq2,
                           ushort* __restrict__ Wc0, ushort* __restrict__ Wc1, ushort* __restrict__ Wc2,
                           float* __restrict__ biasG)
{
    int n = blockIdx.x, tid = threadIdx.x;     // 0..3071
    if (n < 2048) {
        int ublk = n >> 6, gate = (n >> 4) & 3, ui = n & 15;
        int src = gate * 512 + ublk * 16 + ui;
        for (int k = tid; k < 1024; k += 256) {
            float v = (k < 512) ? W_ih[(size_t)src * 512 + k]
                                : W_hh[(size_t)src * 512 + (k - 512)];
            ushort s0, s1, s2; split3(v, &s0, &s1, &s2);
            Wg0[(size_t)n * 1024 + k] = s0;
            Wg1[(size_t)n * 1024 + k] = s1;
            Wg2[(size_t)n * 1024 + k] = s2;
        }
        if (tid == 0) biasG[src] = b_ih[src] + b_hh[src];
    } else if (n < 2560) {
        int n2 = n - 2048;
        for (int k = tid; k < 512; k += 256) {
            ushort s0, s1, s2; split3(Wq[(size_t)n2 * 512 + k], &s0, &s1, &s2);
            Wq0[(size_t)n2 * 512 + k] = s0;
            Wq1[(size_t)n2 * 512 + k] = s1;
            Wq2[(size_t)n2 * 512 + k] = s2;
        }
    } else {
        int n2 = n - 2560;
        for (int k = tid; k < 512; k += 256) {
            ushort s0, s1, s2; split3(Wc[(size_t)n2 * 512 + k], &s0, &s1, &s2);
            Wc0[(size_t)n2 * 512 + k] = s0;
            Wc1[(size_t)n2 * 512 + k] = s1;
            Wc2[(size_t)n2 * 512 + k] = s2;
        }
    }
}

// ---- init: cst = hf0 = h0 = enc.sum(axis=1), all f32 (R17-proven, verbatim) ----
__global__ void init0(const float* __restrict__ home, const float* __restrict__ vis,
                      const float* __restrict__ team,
                      float* __restrict__ cst, float* __restrict__ hf0)
{
    int row = blockIdx.x, tid = threadIdx.x;
    int tau = row / BROWS, r = row % BROWS;
    const float* enc = (tau == 0) ? home : (tau == 1) ? vis : team;
    const float* base = enc + ((size_t)((r % KW) * BSZn + r / KW) * PLY) * 512;
    for (int e = tid; e < 512; e += 256) {
        float s = 0.0f;
        for (int p = 0; p < PLY; ++p) s += base[(size_t)p * 512 + e];
        size_t o = (size_t)row * 512 + e;
        cst[o] = s;
        hf0[o] = s;
    }
}

// ---- gates+q MFMA (R17-proven, verbatim) ----
__global__ __launch_bounds__(256) void gates_mfma(
    const float* __restrict__ home, const float* __restrict__ vis, const float* __restrict__ team,
    const int* __restrict__ hidx, const int* __restrict__ vidx, const int* __restrict__ tidx,
    const float* __restrict__ init_embed,
    const float* __restrict__ hf_in,
    const ushort* __restrict__ Wg0, const ushort* __restrict__ Wg1, const ushort* __restrict__ Wg2,
    const ushort* __restrict__ Wq0, const ushort* __restrict__ Wq1, const ushort* __restrict__ Wq2,
    const float* __restrict__ biasG, const float* __restrict__ bq,
    float* __restrict__ cst, float* __restrict__ hf_out,
    float* __restrict__ Q4, int bn_off, int qslot, int t)
{
    __shared__ char Lds[49152];               // A0|A1|A2 | B0|B1|B2 (8KB each)
    int tid = threadIdx.x;
    int bm = blockIdx.x, bn = blockIdx.y + bn_off;
    bool isq = bn >= 16;
    int w = tid >> 6, lane = tid & 63;
    int wr = w >> 1, wc = w & 1;
    int r0 = bm * 128;
    int nbase = isq ? (bn - 16) * 128 : bn * 128;
    int ldb = isq ? 512 : 1024;
    int kb0 = isq ? 16 : 0;
    int l4 = lane >> 2, lc = lane & 3;        // B loader row-sub / col16
    int srow = tid >> 1, sh = tid & 1;        // A stager: row, 16-float half

    const float* hrow = hf_in + (size_t)(r0 + srow) * 512;
    const float* xrow = init_embed;
    if (!isq && t > 0) {
        int tau = (bm * 128) / BROWS;
        const float* enc = (tau == 0) ? home : (tau == 1) ? vis : team;
        const int* idx = (tau == 0) ? hidx : (tau == 1) ? vidx : tidx;
        int r = r0 + srow - tau * BROWS;
        int j = idx[r * PLY + (t - 1)];
        xrow = enc + ((size_t)((r % KW) * BSZn + r / KW) * PLY + j) * 512;
    }
    const ushort* Bp[3];
    if (isq) { Bp[0] = Wq0; Bp[1] = Wq1; Bp[2] = Wq2; }
    else     { Bp[0] = Wg0; Bp[1] = Wg1; Bp[2] = Wg2; }

    f32x4 acc[4][4];
    #pragma unroll
    for (int i = 0; i < 4; ++i)
        #pragma unroll
        for (int j = 0; j < 4; ++j) acc[i][j] = (f32x4){0.f, 0.f, 0.f, 0.f};

    char* ldsBw = Lds + 24576 + w * 2048;     // per-wave B dest base (plane += 8192)
    char* aw = Lds + srow * 64 + sh * 32;     // per-thread A dest (plane += 8192)

    for (int kb = kb0; kb < 32; ++kb) {
        int kloc = (kb & 15) * 32;
        const float* src = (!isq && kb < 16) ? xrow : hrow;
        float fv[16];
        *(float4*)&fv[0]  = *(const float4*)(src + kloc + sh * 16);
        *(float4*)&fv[4]  = *(const float4*)(src + kloc + sh * 16 + 4);
        *(float4*)&fv[8]  = *(const float4*)(src + kloc + sh * 16 + 8);
        *(float4*)&fv[12] = *(const float4*)(src + kloc + sh * 16 + 12);
        int bofe = isq ? kloc : kb * 32;
        __syncthreads();                      // prev kb's frag reads done
        #pragma unroll
        for (int p = 0; p < 3; ++p) {         // B planes async (proven path)
            gload16(Bp[p] + (size_t)(nbase + w * 32 + l4) * ldb + bofe + lc * 8,
                    ldsBw + p * 8192);
            gload16(Bp[p] + (size_t)(nbase + w * 32 + 16 + l4) * ldb + bofe + lc * 8,
                    ldsBw + p * 8192 + 1024);
        }
        union { ushort u[16]; uint4 v[2]; } u0, u1, u2;
        #pragma unroll
        for (int j2 = 0; j2 < 16; ++j2) split3(fv[j2], &u0.u[j2], &u1.u[j2], &u2.u[j2]);
        *(uint4*)(aw)              = u0.v[0];
        *(uint4*)(aw + 16)         = u0.v[1];
        *(uint4*)(aw + 8192)       = u1.v[0];
        *(uint4*)(aw + 8192 + 16)  = u1.v[1];
        *(uint4*)(aw + 16384)      = u2.v[0];
        *(uint4*)(aw + 16384 + 16) = u2.v[1];
        __syncthreads();                      // drains lgkm + vmcnt

        #pragma unroll
        for (int a = 0; a < 3; ++a) {
            short8v af[4];
            #pragma unroll
            for (int fm = 0; fm < 4; ++fm)
                af[fm] = *(const short8v*)(Lds + a * 8192 +
                           (wr * 64 + fm * 16 + (lane & 15)) * 64 + (lane >> 4) * 16);
            #pragma unroll
            for (int b = 2; b >= 0; --b) {    // smallest products first within group
                if (a + b > 2) continue;
                const char* LdsB = Lds + 24576 + b * 8192;
                short8v bf[4];
                #pragma unroll
                for (int fn = 0; fn < 4; ++fn)
                    bf[fn] = *(const short8v*)(LdsB +
                               (wc * 64 + fn * 16 + (lane & 15)) * 64 + (lane >> 4) * 16);
                #pragma unroll
                for (int fm = 0; fm < 4; ++fm)
                    #pragma unroll
                    for (int fn = 0; fn < 4; ++fn)
                        acc[fm][fn] = __builtin_amdgcn_mfma_f32_16x16x32_bf16(
                            af[fm], bf[fn], acc[fm][fn], 0, 0, 0);
            }
        }
    }

    if (!isq) {
        int u = (bn * 2 + wc) * 16 + (lane & 15);
        float bI = biasG[u], bF = biasG[512 + u], bG = biasG[1024 + u], bO = biasG[1536 + u];
        #pragma unroll
        for (int fm = 0; fm < 4; ++fm) {
            #pragma unroll
            for (int reg = 0; reg < 4; ++reg) {
                int row = r0 + wr * 64 + fm * 16 + (lane >> 4) * 4 + reg;
                float gi = acc[fm][0][reg] + bI;
                float gf = acc[fm][1][reg] + bF;
                float gg = acc[fm][2][reg] + bG;
                float go = acc[fm][3][reg] + bO;
                size_t ci = (size_t)row * 512 + u;
                float c = cst[ci];
                c = sigmoidf_(gf) * c + sigmoidf_(gi) * tanhf(gg);
                float h = sigmoidf_(go) * tanhf(c);
                cst[ci] = c;
                hf_out[ci] = h;
            }
        }
    } else {
        float* Qout = Q4 + (size_t)qslot * RTOT * 512;
        #pragma unroll
        for (int fn = 0; fn < 4; ++fn) {
            int col = nbase + wc * 64 + fn * 16 + (lane & 15);
            float bqv = bq[col];
            #pragma unroll
            for (int fm = 0; fm < 4; ++fm)
                #pragma unroll
                for (int reg = 0; reg < 4; ++reg) {
                    int row = r0 + wr * 64 + fm * 16 + (lane >> 4) * 4 + reg;
                    Qout[(size_t)row * 512 + col] = acc[fm][fn][reg] + bqv;
                }
        }
    }
}

// ---- ctx MFMA v18: ctx = enc @ Wc^T via split3 (clone of gates q-path; K=512) ----
// A = gathered enc rows (f32, in-kernel split3); B = Wc planes (gload16).
// Epilogue: plain f32 store to ctx. Grid (1152, 4).
__global__ __launch_bounds__(256) void ctx_mfma(
    const float* __restrict__ home, const float* __restrict__ vis, const float* __restrict__ team,
    const ushort* __restrict__ Wc0, const ushort* __restrict__ Wc1, const ushort* __restrict__ Wc2,
    float* __restrict__ ctx)
{
    __shared__ char Lds[49152];               // A0|A1|A2 | B0|B1|B2
    int tid = threadIdx.x;
    int bm = blockIdx.x, bn = blockIdx.y;
    int w = tid >> 6, lane = tid & 63;
    int wr = w >> 1, wc = w & 1;
    int r0 = bm * 128;
    int nbase = bn * 128;
    int l4 = lane >> 2, lc = lane & 3;
    int srow = tid >> 1, sh = tid & 1;

    // gathered A row (enc layout)
    int R = r0 + srow;
    int tau = r0 / (BROWS * PLY);
    const float* enc = (tau == 0) ? home : (tau == 1) ? vis : team;
    int rr = R % (BROWS * PLY), r = rr >> 5, p = rr & 31;
    const float* arow = enc + ((size_t)((r % KW) * BSZn + r / KW) * PLY + p) * 512;
    const ushort* Bp[3] = {Wc0, Wc1, Wc2};

    f32x4 acc[4][4];
    #pragma unroll
    for (int i = 0; i < 4; ++i)
        #pragma unroll
        for (int j = 0; j < 4; ++j) acc[i][j] = (f32x4){0.f, 0.f, 0.f, 0.f};

    char* ldsBw = Lds + 24576 + w * 2048;
    char* aw = Lds + srow * 64 + sh * 32;

    for (int kb = 0; kb < 16; ++kb) {
        int kloc = kb * 32;
        float fv[16];
        *(float4*)&fv[0]  = *(const float4*)(arow + kloc + sh * 16);
        *(float4*)&fv[4]  = *(const float4*)(arow + kloc + sh * 16 + 4);
        *(float4*)&fv[8]  = *(const float4*)(arow + kloc + sh * 16 + 8);
        *(float4*)&fv[12] = *(const float4*)(arow + kloc + sh * 16 + 12);
        __syncthreads();
        #pragma unroll
        for (int pp = 0; pp < 3; ++pp) {
            gload16(Bp[pp] + (size_t)(nbase + w * 32 + l4) * 512 + kloc + lc * 8,
                    ldsBw + pp * 8192);
            gload16(Bp[pp] + (size_t)(nbase + w * 32 + 16 + l4) * 512 + kloc + lc * 8,
                    ldsBw + pp * 8192 + 1024);
        }
        union { ushort u[16]; uint4 v[2]; } u0, u1, u2;
        #pragma unroll
        for (int j2 = 0; j2 < 16; ++j2) split3(fv[j2], &u0.u[j2], &u1.u[j2], &u2.u[j2]);
        *(uint4*)(aw)              = u0.v[0];
        *(uint4*)(aw + 16)         = u0.v[1];
        *(uint4*)(aw + 8192)       = u1.v[0];
        *(uint4*)(aw + 8192 + 16)  = u1.v[1];
        *(uint4*)(aw + 16384)      = u2.v[0];
        *(uint4*)(aw + 16384 + 16) = u2.v[1];
        __syncthreads();

        #pragma unroll
        for (int a = 0; a < 3; ++a) {
            short8v af[4];
            #pragma unroll
            for (int fm = 0; fm < 4; ++fm)
                af[fm] = *(const short8v*)(Lds + a * 8192 +
                           (wr * 64 + fm * 16 + (lane & 15)) * 64 + (lane >> 4) * 16);
            #pragma unroll
            for (int b = 2; b >= 0; --b) {
                if (a + b > 2) continue;
                const char* LdsB = Lds + 24576 + b * 8192;
                short8v bf[4];
                #pragma unroll
                for (int fn = 0; fn < 4; ++fn)
                    bf[fn] = *(const short8v*)(LdsB +
                               (wc * 64 + fn * 16 + (lane & 15)) * 64 + (lane >> 4) * 16);
                #pragma unroll
                for (int fm = 0; fm < 4; ++fm)
                    #pragma unroll
                    for (int fn = 0; fn < 4; ++fn)
                        acc[fm][fn] = __builtin_amdgcn_mfma_f32_16x16x32_bf16(
                            af[fm], bf[fn], acc[fm][fn], 0, 0, 0);
            }
        }
    }

    #pragma unroll
    for (int fn = 0; fn < 4; ++fn) {
        int col = nbase + wc * 64 + fn * 16 + (lane & 15);
        #pragma unroll
        for (int fm = 0; fm < 4; ++fm)
            #pragma unroll
            for (int reg = 0; reg < 4; ++reg) {
                int row = r0 + wr * 64 + fm * 16 + (lane >> 4) * 4 + reg;
                ctx[(size_t)row * 512 + col] = acc[fm][fn][reg];
            }
    }
}

// ---- attention, 4 steps per ctx load (R17-proven, verbatim) ----
__global__ __launch_bounds__(256) void attn4r(
    const float* __restrict__ Q4, const float* __restrict__ ctx,
    const float* __restrict__ vvec, float* __restrict__ out, int tbase)
{
    int row = blockIdx.x, tid = threadIdx.x;
    int w = tid >> 6, lane = tid & 63;
    __shared__ float scs[4][PLY];

    float qv[4][8], vv[8];
    #pragma unroll
    for (int s = 0; s < 4; ++s) {
        const float* q = Q4 + ((size_t)s * RTOT + row) * 512 + lane * 8;
        *(float4*)&qv[s][0] = *(const float4*)(q);
        *(float4*)&qv[s][4] = *(const float4*)(q + 4);
    }
    *(float4*)&vv[0] = *(const float4*)(vvec + lane * 8);
    *(float4*)&vv[4] = *(const float4*)(vvec + lane * 8 + 4);
    const float* ctxr = ctx + (size_t)row * PLY * 512 + lane * 8;

    for (int pp = 0; pp < 8; ++pp) {
        int p = w * 8 + pp;
        const float* cp = ctxr + (size_t)p * 512;
        float cv[8];
        *(float4*)&cv[0] = *(const float4*)(cp);
        *(float4*)&cv[4] = *(const float4*)(cp + 4);
        float a[4] = {0.f, 0.f, 0.f, 0.f};
        #pragma unroll
        for (int j = 0; j < 8; ++j) {
            float c = cv[j], ve = vv[j];
            #pragma unroll
            for (int s = 0; s < 4; ++s)
                a[s] += tanhf(qv[s][j] + c) * ve;
        }
        #pragma unroll
        for (int off = 1; off < 64; off <<= 1) {
            #pragma unroll
            for (int s = 0; s < 4; ++s) a[s] += __shfl_xor(a[s], off);
        }
        if (lane == 0) {
            #pragma unroll
            for (int s = 0; s < 4; ++s) scs[s][p] = a[s];
        }
    }
    __syncthreads();

    if (tid < 128) {
        int w2 = tid >> 5, l = tid & 31;
        float x = scs[w2][l];
        float bvv = x; int bi = l;
        #pragma unroll
        for (int off = 1; off < 32; off <<= 1) {
            float ov = __shfl_xor(bvv, off, 32);
            int oi = __shfl_xor(bi, off, 32);
            if (ov > bvv || (ov == bvv && oi < bi)) { bvv = ov; bi = oi; }
        }
        float s = expf(x - bvv);
        #pragma unroll
        for (int off = 1; off < 32; off <<= 1) s += __shfl_xor(s, off, 32);
        float lse = logf(s);
        int t = tbase + w2;
        int tau = row / BROWS, r = row % BROWS;
        out[(size_t)tau * (BROWS * 1024) + (size_t)r * 1024 + t * 32 + l] = x - bvv - lse;
        if (l == 0)
            out[(size_t)3 * (BROWS * 1024) + (size_t)tau * (BROWS * 32) + r * 32 + t] = (float)bi;
    }
}

extern "C" void kernel_launch(void* const* d_in, const int* in_sizes, int n_in,
                              void* d_out, int out_size, void* d_ws, size_t ws_size,
                              hipStream_t stream)
{
    const float* home = (const float*)d_in[0];
    const int*   hidx = (const int*)d_in[1];
    const float* vis  = (const float*)d_in[2];
    const int*   vidx = (const int*)d_in[3];
    const float* team = (const float*)d_in[4];
    const int*   tidx = (const int*)d_in[5];
    const float* init_embed = (const float*)d_in[6];
    const float* W_ih = (const float*)d_in[7];
    const float* W_hh = (const float*)d_in[8];
    const float* b_ih = (const float*)d_in[9];
    const float* b_hh = (const float*)d_in[10];
    const float* Wq   = (const float*)d_in[11];
    const float* bq   = (const float*)d_in[12];
    const float* Wc   = (const float*)d_in[13];
    const float* vvec = (const float*)d_in[14];
    float* out = (float*)d_out;
    (void)in_sizes; (void)n_in; (void)out_size; (void)ws_size;

    char* wsb = (char*)d_ws;
    float* ctx   = (float*)wsb; wsb += (size_t)RTOT * PLY * 512 * 4;   // 302.0 MB
    float* cst   = (float*)wsb; wsb += (size_t)RTOT * 512 * 4;         // 9.4 MB
    float* Q4    = (float*)wsb; wsb += (size_t)4 * RTOT * 512 * 4;     // 37.7 MB
    float* biasG = (float*)wsb; wsb += 2048 * 4;
    ushort* Wg[3], *Wq3[3], *Wc3[3];
    for (int i = 0; i < 3; ++i) { Wg[i]  = (ushort*)wsb; wsb += (size_t)2048 * 1024 * 2; } // 12.6 MB
    for (int i = 0; i < 3; ++i) { Wq3[i] = (ushort*)wsb; wsb += (size_t)512 * 512 * 2; }   // 1.6 MB
    for (int i = 0; i < 3; ++i) { Wc3[i] = (ushort*)wsb; wsb += (size_t)512 * 512 * 2; }   // 1.6 MB
    float* hf[2];
    for (int b = 0; b < 2; ++b) { hf[b] = (float*)wsb; wsb += (size_t)RTOT * 512 * 4; }    // 18.9 MB
    // total 383.8 MB (< 388.0 MB proven in R1)

    prep_split<<<3072, 256, 0, stream>>>(W_ih, W_hh, Wq, Wc, b_ih, b_hh,
                                         Wg[0], Wg[1], Wg[2], Wq3[0], Wq3[1], Wq3[2],
                                         Wc3[0], Wc3[1], Wc3[2], biasG);
    init0<<<RTOT, 256, 0, stream>>>(home, vis, team, cst, hf[1]);
    ctx_mfma<<<dim3(RTOT * PLY / 128, 4), 256, 0, stream>>>(
        home, vis, team, Wc3[0], Wc3[1], Wc3[2], ctx);

    for (int t = 0; t < 32; ++t) {
        int hin = (t + 1) & 1, hout = t & 1;
        int gy = 16 + ((t >= 1) ? 4 : 0);      // t>=1: fuse q_{t-1} (A == hf[hin])
        gates_mfma<<<dim3(36, gy), 256, 0, stream>>>(
            home, vis, team, hidx, vidx, tidx, init_embed,
            hf[hin],
            Wg[0], Wg[1], Wg[2], Wq3[0], Wq3[1], Wq3[2],
            biasG, bq, cst, hf[hout],
            Q4, 0, (t - 1) & 3, t);
        if (t >= 4 && (t & 3) == 0)           // q(t-4..t-1) in slots 0..3
            attn4r<<<RTOT, 256, 0, stream>>>(Q4, ctx, vvec, out, t - 4);
    }
    // tail: q_31 from h_31 (hf[1]); q-only (bn_off=16), slot 3
    gates_mfma<<<dim3(36, 4), 256, 0, stream>>>(
        home, vis, team, hidx, vidx, tidx, init_embed,
        hf[1],
        Wg[0], Wg[1], Wg[2], Wq3[0], Wq3[1], Wq3[2],
        biasG, bq, cst, hf[0],
        Q4, 16, 3, 32);
    attn4r<<<RTOT, 256, 0, stream>>>(Q4, ctx, vvec, out, 28);
}

// Round 19
// 6442.162 us; speedup vs baseline: 1.3380x; 1.1038x over previous
//
#include <hip/hip_runtime.h>
#include <hip/hip_bf16.h>
#include <math.h>

#define KW 24
#define BSZn 64
#define PLY 32
#define BROWS 1536            // BSZ*KW rows per task
#define RTOT 4608             // 3*BROWS

typedef __attribute__((ext_vector_type(8))) short short8v;  // 8 bf16 (4 VGPRs)
typedef __attribute__((ext_vector_type(4))) float f32x4;

__device__ __forceinline__ float sigmoidf_(float x) { return 1.0f / (1.0f + expf(-x)); }

// fast tanh for the ATTENTION path only (scores; error ~3e-7 rel, no recurrence).
// tanh(x) = (e^2x - 1) / (e^2x + 1); clamp keeps e^2x finite (tanh==+-1.0f beyond |x|~9).
__device__ __forceinline__ float tanh_fast(float x)
{
    float xc = fminf(fmaxf(x, -40.0f), 40.0f);
    float t = __expf(2.0f * xc);
    return (t - 1.0f) * __builtin_amdgcn_rcpf(t + 1.0f);
}

// async global->LDS, 16B/lane; LDS dest = wave-uniform base + lane*16 (HW scatter)
__device__ __forceinline__ void gload16(const void* g, void* l)
{
    __builtin_amdgcn_global_load_lds(
        (__attribute__((address_space(1))) void*)g,
        (__attribute__((address_space(3))) void*)l, 16, 0, 0);
}

// exact 3-way bf16 split: v = s0 + s1 + s2 + O(2^-26 v)
__device__ __forceinline__ void split3(float v, ushort* a, ushort* b, ushort* c)
{
    __hip_bfloat16 h1 = __float2bfloat16(v);  float f1 = __bfloat162float(h1);
    float r1 = v - f1;
    __hip_bfloat16 h2 = __float2bfloat16(r1); float f2 = __bfloat162float(h2);
    float r2 = r1 - f2;
    __hip_bfloat16 h3 = __float2bfloat16(r2);
    *a = *(ushort*)&h1; *b = *(ushort*)&h2; *c = *(ushort*)&h3;
}

// ---- weights prep (R18-proven, verbatim) ----
__global__ void prep_split(const float* __restrict__ W_ih, const float* __restrict__ W_hh,
                           const float* __restrict__ Wq, const float* __restrict__ Wc,
                           const float* __restrict__ b_ih, const float* __restrict__ b_hh,
                           ushort* __restrict__ Wg0, ushort* __restrict__ Wg1, ushort* __restrict__ Wg2,
                           ushort* __restrict__ Wq0, ushort* __restrict__ Wq1, ushort* __restrict__ Wq2,
                           ushort* __restrict__ Wc0, ushort* __restrict__ Wc1, ushort* __restrict__ Wc2,
                           float* __restrict__ biasG)
{
    int n = blockIdx.x, tid = threadIdx.x;     // 0..3071
    if (n < 2048) {
        int ublk = n >> 6, gate = (n >> 4) & 3, ui = n & 15;
        int src = gate * 512 + ublk * 16 + ui;
        for (int k = tid; k < 1024; k += 256) {
            float v = (k < 512) ? W_ih[(size_t)src * 512 + k]
                                : W_hh[(size_t)src * 512 + (k - 512)];
            ushort s0, s1, s2; split3(v, &s0, &s1, &s2);
            Wg0[(size_t)n * 1024 + k] = s0;
            Wg1[(size_t)n * 1024 + k] = s1;
            Wg2[(size_t)n * 1024 + k] = s2;
        }
        if (tid == 0) biasG[src] = b_ih[src] + b_hh[src];
    } else if (n < 2560) {
        int n2 = n - 2048;
        for (int k = tid; k < 512; k += 256) {
            ushort s0, s1, s2; split3(Wq[(size_t)n2 * 512 + k], &s0, &s1, &s2);
            Wq0[(size_t)n2 * 512 + k] = s0;
            Wq1[(size_t)n2 * 512 + k] = s1;
            Wq2[(size_t)n2 * 512 + k] = s2;
        }
    } else {
        int n2 = n - 2560;
        for (int k = tid; k < 512; k += 256) {
            ushort s0, s1, s2; split3(Wc[(size_t)n2 * 512 + k], &s0, &s1, &s2);
            Wc0[(size_t)n2 * 512 + k] = s0;
            Wc1[(size_t)n2 * 512 + k] = s1;
            Wc2[(size_t)n2 * 512 + k] = s2;
        }
    }
}

// ---- init: cst = hf0 = h0 = enc.sum(axis=1), all f32 (R17-proven, verbatim) ----
__global__ void init0(const float* __restrict__ home, const float* __restrict__ vis,
                      const float* __restrict__ team,
                      float* __restrict__ cst, float* __restrict__ hf0)
{
    int row = blockIdx.x, tid = threadIdx.x;
    int tau = row / BROWS, r = row % BROWS;
    const float* enc = (tau == 0) ? home : (tau == 1) ? vis : team;
    const float* base = enc + ((size_t)((r % KW) * BSZn + r / KW) * PLY) * 512;
    for (int e = tid; e < 512; e += 256) {
        float s = 0.0f;
        for (int p = 0; p < PLY; ++p) s += base[(size_t)p * 512 + e];
        size_t o = (size_t)row * 512 + e;
        cst[o] = s;
        hf0[o] = s;
    }
}

// ---- gates+q MFMA (R17-proven, verbatim) ----
__global__ __launch_bounds__(256) void gates_mfma(
    const float* __restrict__ home, const float* __restrict__ vis, const float* __restrict__ team,
    const int* __restrict__ hidx, const int* __restrict__ vidx, const int* __restrict__ tidx,
    const float* __restrict__ init_embed,
    const float* __restrict__ hf_in,
    const ushort* __restrict__ Wg0, const ushort* __restrict__ Wg1, const ushort* __restrict__ Wg2,
    const ushort* __restrict__ Wq0, const ushort* __restrict__ Wq1, const ushort* __restrict__ Wq2,
    const float* __restrict__ biasG, const float* __restrict__ bq,
    float* __restrict__ cst, float* __restrict__ hf_out,
    float* __restrict__ Q4, int bn_off, int qslot, int t)
{
    __shared__ char Lds[49152];               // A0|A1|A2 | B0|B1|B2 (8KB each)
    int tid = threadIdx.x;
    int bm = blockIdx.x, bn = blockIdx.y + bn_off;
    bool isq = bn >= 16;
    int w = tid >> 6, lane = tid & 63;
    int wr = w >> 1, wc = w & 1;
    int r0 = bm * 128;
    int nbase = isq ? (bn - 16) * 128 : bn * 128;
    int ldb = isq ? 512 : 1024;
    int kb0 = isq ? 16 : 0;
    int l4 = lane >> 2, lc = lane & 3;        // B loader row-sub / col16
    int srow = tid >> 1, sh = tid & 1;        // A stager: row, 16-float half

    const float* hrow = hf_in + (size_t)(r0 + srow) * 512;
    const float* xrow = init_embed;
    if (!isq && t > 0) {
        int tau = (bm * 128) / BROWS;
        const float* enc = (tau == 0) ? home : (tau == 1) ? vis : team;
        const int* idx = (tau == 0) ? hidx : (tau == 1) ? vidx : tidx;
        int r = r0 + srow - tau * BROWS;
        int j = idx[r * PLY + (t - 1)];
        xrow = enc + ((size_t)((r % KW) * BSZn + r / KW) * PLY + j) * 512;
    }
    const ushort* Bp[3];
    if (isq) { Bp[0] = Wq0; Bp[1] = Wq1; Bp[2] = Wq2; }
    else     { Bp[0] = Wg0; Bp[1] = Wg1; Bp[2] = Wg2; }

    f32x4 acc[4][4];
    #pragma unroll
    for (int i = 0; i < 4; ++i)
        #pragma unroll
        for (int j = 0; j < 4; ++j) acc[i][j] = (f32x4){0.f, 0.f, 0.f, 0.f};

    char* ldsBw = Lds + 24576 + w * 2048;     // per-wave B dest base (plane += 8192)
    char* aw = Lds + srow * 64 + sh * 32;     // per-thread A dest (plane += 8192)

    for (int kb = kb0; kb < 32; ++kb) {
        int kloc = (kb & 15) * 32;
        const float* src = (!isq && kb < 16) ? xrow : hrow;
        float fv[16];
        *(float4*)&fv[0]  = *(const float4*)(src + kloc + sh * 16);
        *(float4*)&fv[4]  = *(const float4*)(src + kloc + sh * 16 + 4);
        *(float4*)&fv[8]  = *(const float4*)(src + kloc + sh * 16 + 8);
        *(float4*)&fv[12] = *(const float4*)(src + kloc + sh * 16 + 12);
        int bofe = isq ? kloc : kb * 32;
        __syncthreads();                      // prev kb's frag reads done
        #pragma unroll
        for (int p = 0; p < 3; ++p) {         // B planes async (proven path)
            gload16(Bp[p] + (size_t)(nbase + w * 32 + l4) * ldb + bofe + lc * 8,
                    ldsBw + p * 8192);
            gload16(Bp[p] + (size_t)(nbase + w * 32 + 16 + l4) * ldb + bofe + lc * 8,
                    ldsBw + p * 8192 + 1024);
        }
        union { ushort u[16]; uint4 v[2]; } u0, u1, u2;
        #pragma unroll
        for (int j2 = 0; j2 < 16; ++j2) split3(fv[j2], &u0.u[j2], &u1.u[j2], &u2.u[j2]);
        *(uint4*)(aw)              = u0.v[0];
        *(uint4*)(aw + 16)         = u0.v[1];
        *(uint4*)(aw + 8192)       = u1.v[0];
        *(uint4*)(aw + 8192 + 16)  = u1.v[1];
        *(uint4*)(aw + 16384)      = u2.v[0];
        *(uint4*)(aw + 16384 + 16) = u2.v[1];
        __syncthreads();                      // drains lgkm + vmcnt

        #pragma unroll
        for (int a = 0; a < 3; ++a) {
            short8v af[4];
            #pragma unroll
            for (int fm = 0; fm < 4; ++fm)
                af[fm] = *(const short8v*)(Lds + a * 8192 +
                           (wr * 64 + fm * 16 + (lane & 15)) * 64 + (lane >> 4) * 16);
            #pragma unroll
            for (int b = 2; b >= 0; --b) {    // smallest products first within group
                if (a + b > 2) continue;
                const char* LdsB = Lds + 24576 + b * 8192;
                short8v bf[4];
                #pragma unroll
                for (int fn = 0; fn < 4; ++fn)
                    bf[fn] = *(const short8v*)(LdsB +
                               (wc * 64 + fn * 16 + (lane & 15)) * 64 + (lane >> 4) * 16);
                #pragma unroll
                for (int fm = 0; fm < 4; ++fm)
                    #pragma unroll
                    for (int fn = 0; fn < 4; ++fn)
                        acc[fm][fn] = __builtin_amdgcn_mfma_f32_16x16x32_bf16(
                            af[fm], bf[fn], acc[fm][fn], 0, 0, 0);
            }
        }
    }

    if (!isq) {
        int u = (bn * 2 + wc) * 16 + (lane & 15);
        float bI = biasG[u], bF = biasG[512 + u], bG = biasG[1024 + u], bO = biasG[1536 + u];
        #pragma unroll
        for (int fm = 0; fm < 4; ++fm) {
            #pragma unroll
            for (int reg = 0; reg < 4; ++reg) {
                int row = r0 + wr * 64 + fm * 16 + (lane >> 4) * 4 + reg;
                float gi = acc[fm][0][reg] + bI;
                float gf = acc[fm][1][reg] + bF;
                float gg = acc[fm][2][reg] + bG;
                float go = acc[fm][3][reg] + bO;
                size_t ci = (size_t)row * 512 + u;
                float c = cst[ci];
                c = sigmoidf_(gf) * c + sigmoidf_(gi) * tanhf(gg);
                float h = sigmoidf_(go) * tanhf(c);
                cst[ci] = c;
                hf_out[ci] = h;
            }
        }
    } else {
        float* Qout = Q4 + (size_t)qslot * RTOT * 512;
        #pragma unroll
        for (int fn = 0; fn < 4; ++fn) {
            int col = nbase + wc * 64 + fn * 16 + (lane & 15);
            float bqv = bq[col];
            #pragma unroll
            for (int fm = 0; fm < 4; ++fm)
                #pragma unroll
                for (int reg = 0; reg < 4; ++reg) {
                    int row = r0 + wr * 64 + fm * 16 + (lane >> 4) * 4 + reg;
                    Qout[(size_t)row * 512 + col] = acc[fm][fn][reg] + bqv;
                }
        }
    }
}

// ---- ctx MFMA (R18-proven, verbatim) ----
__global__ __launch_bounds__(256) void ctx_mfma(
    const float* __restrict__ home, const float* __restrict__ vis, const float* __restrict__ team,
    const ushort* __restrict__ Wc0, const ushort* __restrict__ Wc1, const ushort* __restrict__ Wc2,
    float* __restrict__ ctx)
{
    __shared__ char Lds[49152];               // A0|A1|A2 | B0|B1|B2
    int tid = threadIdx.x;
    int bm = blockIdx.x, bn = blockIdx.y;
    int w = tid >> 6, lane = tid & 63;
    int wr = w >> 1, wc = w & 1;
    int r0 = bm * 128;
    int nbase = bn * 128;
    int l4 = lane >> 2, lc = lane & 3;
    int srow = tid >> 1, sh = tid & 1;

    int R = r0 + srow;
    int tau = r0 / (BROWS * PLY);
    const float* enc = (tau == 0) ? home : (tau == 1) ? vis : team;
    int rr = R % (BROWS * PLY), r = rr >> 5, p = rr & 31;
    const float* arow = enc + ((size_t)((r % KW) * BSZn + r / KW) * PLY + p) * 512;
    const ushort* Bp[3] = {Wc0, Wc1, Wc2};

    f32x4 acc[4][4];
    #pragma unroll
    for (int i = 0; i < 4; ++i)
        #pragma unroll
        for (int j = 0; j < 4; ++j) acc[i][j] = (f32x4){0.f, 0.f, 0.f, 0.f};

    char* ldsBw = Lds + 24576 + w * 2048;
    char* aw = Lds + srow * 64 + sh * 32;

    for (int kb = 0; kb < 16; ++kb) {
        int kloc = kb * 32;
        float fv[16];
        *(float4*)&fv[0]  = *(const float4*)(arow + kloc + sh * 16);
        *(float4*)&fv[4]  = *(const float4*)(arow + kloc + sh * 16 + 4);
        *(float4*)&fv[8]  = *(const float4*)(arow + kloc + sh * 16 + 8);
        *(float4*)&fv[12] = *(const float4*)(arow + kloc + sh * 16 + 12);
        __syncthreads();
        #pragma unroll
        for (int pp = 0; pp < 3; ++pp) {
            gload16(Bp[pp] + (size_t)(nbase + w * 32 + l4) * 512 + kloc + lc * 8,
                    ldsBw + pp * 8192);
            gload16(Bp[pp] + (size_t)(nbase + w * 32 + 16 + l4) * 512 + kloc + lc * 8,
                    ldsBw + pp * 8192 + 1024);
        }
        union { ushort u[16]; uint4 v[2]; } u0, u1, u2;
        #pragma unroll
        for (int j2 = 0; j2 < 16; ++j2) split3(fv[j2], &u0.u[j2], &u1.u[j2], &u2.u[j2]);
        *(uint4*)(aw)              = u0.v[0];
        *(uint4*)(aw + 16)         = u0.v[1];
        *(uint4*)(aw + 8192)       = u1.v[0];
        *(uint4*)(aw + 8192 + 16)  = u1.v[1];
        *(uint4*)(aw + 16384)      = u2.v[0];
        *(uint4*)(aw + 16384 + 16) = u2.v[1];
        __syncthreads();

        #pragma unroll
        for (int a = 0; a < 3; ++a) {
            short8v af[4];
            #pragma unroll
            for (int fm = 0; fm < 4; ++fm)
                af[fm] = *(const short8v*)(Lds + a * 8192 +
                           (wr * 64 + fm * 16 + (lane & 15)) * 64 + (lane >> 4) * 16);
            #pragma unroll
            for (int b = 2; b >= 0; --b) {
                if (a + b > 2) continue;
                const char* LdsB = Lds + 24576 + b * 8192;
                short8v bf[4];
                #pragma unroll
                for (int fn = 0; fn < 4; ++fn)
                    bf[fn] = *(const short8v*)(LdsB +
                               (wc * 64 + fn * 16 + (lane & 15)) * 64 + (lane >> 4) * 16);
                #pragma unroll
                for (int fm = 0; fm < 4; ++fm)
                    #pragma unroll
                    for (int fn = 0; fn < 4; ++fn)
                        acc[fm][fn] = __builtin_amdgcn_mfma_f32_16x16x32_bf16(
                            af[fm], bf[fn], acc[fm][fn], 0, 0, 0);
            }
        }
    }

    #pragma unroll
    for (int fn = 0; fn < 4; ++fn) {
        int col = nbase + wc * 64 + fn * 16 + (lane & 15);
        #pragma unroll
        for (int fm = 0; fm < 4; ++fm)
            #pragma unroll
            for (int reg = 0; reg < 4; ++reg) {
                int row = r0 + wr * 64 + fm * 16 + (lane >> 4) * 4 + reg;
                ctx[(size_t)row * 512 + col] = acc[fm][fn][reg];
            }
    }
}

// ---- attention, 4 steps per ctx load; R19: tanh_fast in score loop ----
__global__ __launch_bounds__(256) void attn4r(
    const float* __restrict__ Q4, const float* __restrict__ ctx,
    const float* __restrict__ vvec, float* __restrict__ out, int tbase)
{
    int row = blockIdx.x, tid = threadIdx.x;
    int w = tid >> 6, lane = tid & 63;
    __shared__ float scs[4][PLY];

    float qv[4][8], vv[8];
    #pragma unroll
    for (int s = 0; s < 4; ++s) {
        const float* q = Q4 + ((size_t)s * RTOT + row) * 512 + lane * 8;
        *(float4*)&qv[s][0] = *(const float4*)(q);
        *(float4*)&qv[s][4] = *(const float4*)(q + 4);
    }
    *(float4*)&vv[0] = *(const float4*)(vvec + lane * 8);
    *(float4*)&vv[4] = *(const float4*)(vvec + lane * 8 + 4);
    const float* ctxr = ctx + (size_t)row * PLY * 512 + lane * 8;

    for (int pp = 0; pp < 8; ++pp) {
        int p = w * 8 + pp;
        const float* cp = ctxr + (size_t)p * 512;
        float cv[8];
        *(float4*)&cv[0] = *(const float4*)(cp);
        *(float4*)&cv[4] = *(const float4*)(cp + 4);
        float a[4] = {0.f, 0.f, 0.f, 0.f};
        #pragma unroll
        for (int j = 0; j < 8; ++j) {
            float c = cv[j], ve = vv[j];
            #pragma unroll
            for (int s = 0; s < 4; ++s)
                a[s] += tanh_fast(qv[s][j] + c) * ve;
        }
        #pragma unroll
        for (int off = 1; off < 64; off <<= 1) {
            #pragma unroll
            for (int s = 0; s < 4; ++s) a[s] += __shfl_xor(a[s], off);
        }
        if (lane == 0) {
            #pragma unroll
            for (int s = 0; s < 4; ++s) scs[s][p] = a[s];
        }
    }
    __syncthreads();

    if (tid < 128) {
        int w2 = tid >> 5, l = tid & 31;
        float x = scs[w2][l];
        float bvv = x; int bi = l;
        #pragma unroll
        for (int off = 1; off < 32; off <<= 1) {
            float ov = __shfl_xor(bvv, off, 32);
            int oi = __shfl_xor(bi, off, 32);
            if (ov > bvv || (ov == bvv && oi < bi)) { bvv = ov; bi = oi; }
        }
        float s = expf(x - bvv);
        #pragma unroll
        for (int off = 1; off < 32; off <<= 1) s += __shfl_xor(s, off, 32);
        float lse = logf(s);
        int t = tbase + w2;
        int tau = row / BROWS, r = row % BROWS;
        out[(size_t)tau * (BROWS * 1024) + (size_t)r * 1024 + t * 32 + l] = x - bvv - lse;
        if (l == 0)
            out[(size_t)3 * (BROWS * 1024) + (size_t)tau * (BROWS * 32) + r * 32 + t] = (float)bi;
    }
}

extern "C" void kernel_launch(void* const* d_in, const int* in_sizes, int n_in,
                              void* d_out, int out_size, void* d_ws, size_t ws_size,
                              hipStream_t stream)
{
    const float* home = (const float*)d_in[0];
    const int*   hidx = (const int*)d_in[1];
    const float* vis  = (const float*)d_in[2];
    const int*   vidx = (const int*)d_in[3];
    const float* team = (const float*)d_in[4];
    const int*   tidx = (const int*)d_in[5];
    const float* init_embed = (const float*)d_in[6];
    const float* W_ih = (const float*)d_in[7];
    const float* W_hh = (const float*)d_in[8];
    const float* b_ih = (const float*)d_in[9];
    const float* b_hh = (const float*)d_in[10];
    const float* Wq   = (const float*)d_in[11];
    const float* bq   = (const float*)d_in[12];
    const float* Wc   = (const float*)d_in[13];
    const float* vvec = (const float*)d_in[14];
    float* out = (float*)d_out;
    (void)in_sizes; (void)n_in; (void)out_size; (void)ws_size;

    char* wsb = (char*)d_ws;
    float* ctx   = (float*)wsb; wsb += (size_t)RTOT * PLY * 512 * 4;   // 302.0 MB
    float* cst   = (float*)wsb; wsb += (size_t)RTOT * 512 * 4;         // 9.4 MB
    float* Q4    = (float*)wsb; wsb += (size_t)4 * RTOT * 512 * 4;     // 37.7 MB
    float* biasG = (float*)wsb; wsb += 2048 * 4;
    ushort* Wg[3], *Wq3[3], *Wc3[3];
    for (int i = 0; i < 3; ++i) { Wg[i]  = (ushort*)wsb; wsb += (size_t)2048 * 1024 * 2; } // 12.6 MB
    for (int i = 0; i < 3; ++i) { Wq3[i] = (ushort*)wsb; wsb += (size_t)512 * 512 * 2; }   // 1.6 MB
    for (int i = 0; i < 3; ++i) { Wc3[i] = (ushort*)wsb; wsb += (size_t)512 * 512 * 2; }   // 1.6 MB
    float* hf[2];
    for (int b = 0; b < 2; ++b) { hf[b] = (float*)wsb; wsb += (size_t)RTOT * 512 * 4; }    // 18.9 MB
    // total 383.8 MB (< 388.0 MB proven in R1)

    prep_split<<<3072, 256, 0, stream>>>(W_ih, W_hh, Wq, Wc, b_ih, b_hh,
                                         Wg[0], Wg[1], Wg[2], Wq3[0], Wq3[1], Wq3[2],
                                         Wc3[0], Wc3[1], Wc3[2], biasG);
    init0<<<RTOT, 256, 0, stream>>>(home, vis, team, cst, hf[1]);
    ctx_mfma<<<dim3(RTOT * PLY / 128, 4), 256, 0, stream>>>(
        home, vis, team, Wc3[0], Wc3[1], Wc3[2], ctx);

    for (int t = 0; t < 32; ++t) {
        int hin = (t + 1) & 1, hout = t & 1;
        int gy = 16 + ((t >= 1) ? 4 : 0);      // t>=1: fuse q_{t-1} (A == hf[hin])
        gates_mfma<<<dim3(36, gy), 256, 0, stream>>>(
            home, vis, team, hidx, vidx, tidx, init_embed,
            hf[hin],
            Wg[0], Wg[1], Wg[2], Wq3[0], Wq3[1], Wq3[2],
            biasG, bq, cst, hf[hout],
            Q4, 0, (t - 1) & 3, t);
        if (t >= 4 && (t & 3) == 0)           // q(t-4..t-1) in slots 0..3
            attn4r<<<RTOT, 256, 0, stream>>>(Q4, ctx, vvec, out, t - 4);
    }
    // tail: q_31 from h_31 (hf[1]); q-only (bn_off=16), slot 3
    gates_mfma<<<dim3(36, 4), 256, 0, stream>>>(
        home, vis, team, hidx, vidx, tidx, init_embed,
        hf[1],
        Wg[0], Wg[1], Wg[2], Wq3[0], Wq3[1], Wq3[2],
        biasG, bq, cst, hf[0],
        Q4, 16, 3, 32);
    attn4r<<<RTOT, 256, 0, stream>>>(Q4, ctx, vvec, out, 28);
}